// Round 20
// baseline (130.682 us; speedup 1.0000x reference)
//
#include <hip/hip_runtime.h>
#include <math.h>

#define B_    2
#define LSEQ  1024
#define DM    512
#define DI    1024
#define NS    64
#define TC    32
#define NC    (LSEQ/TC)     // 32
#define LDP   72            // padded stride for corrK tiles only

typedef __bf16 bf16x8 __attribute__((ext_vector_type(8)));
typedef float  f32x4  __attribute__((ext_vector_type(4)));

// fast-math transcendentals: native v_exp_f32 / v_log_f32 / v_rcp_f32.
__device__ __forceinline__ float fexp(float x)   { return __expf(x); }
__device__ __forceinline__ float sp_f(float x)   { return fmaxf(x, 0.f) + __logf(1.f + __expf(-fabsf(x))); }
__device__ __forceinline__ float silu_f(float x) { return x * __builtin_amdgcn_rcpf(1.f + __expf(-x)); }
__device__ __forceinline__ unsigned short f2bf(float f) {
    unsigned int u = __float_as_uint(f);
    u += 0x7FFF + ((u >> 16) & 1);          // RNE
    return (unsigned short)(u >> 16);
}
__device__ __forceinline__ float bf2f(unsigned short h) {
    return __uint_as_float(((unsigned int)h) << 16);
}
// async global->LDS, 16 B per lane; LDS dest = wave-uniform base + lane*16
__device__ __forceinline__ void gload16(const void* g, void* l) {
    __builtin_amdgcn_global_load_lds(
        (const __attribute__((address_space(1))) unsigned int*)g,
        (__attribute__((address_space(3))) unsigned int*)l, 16, 0, 0);
}

// ---------------------------------------------------------------------------
// All 4 f32->bf16 casts in one launch (3712 blocks exactly).
// ---------------------------------------------------------------------------
__global__ __launch_bounds__(256) void castall(
    const float* __restrict__ x, const float* __restrict__ W_in,
    const float* __restrict__ W_xproj, const float* __restrict__ W_out,
    unsigned short* __restrict__ xb, unsigned short* __restrict__ winb,
    unsigned short* __restrict__ wxb, unsigned short* __restrict__ wob)
{
    int i = (blockIdx.x * 256 + threadIdx.x) * 4;
    const float* s; unsigned short* dst; int off;
    if (i < 1048576)      { s = x;       dst = xb;   off = i; }
    else if (i < 2097152) { s = W_in;    dst = winb; off = i - 1048576; }
    else if (i < 3276800) { s = W_xproj; dst = wxb;  off = i - 2097152; }
    else                  { s = W_out;   dst = wob;  off = i - 3276800; }
    float4 v = *(const float4*)(s + off);
    ushort4 o;
    o.x = f2bf(v.x); o.y = f2bf(v.y); o.z = f2bf(v.z); o.w = f2bf(v.w);
    *(ushort4*)(dst + off) = o;
}

// ---------------------------------------------------------------------------
// bf16 MFMA GEMM: 64x64 tile, BK=64, 4 waves in 2x2 (each 32x32, acc[2][2]).
// R17 structure (proven best, 122.7 us): gload_lds + both-sides XOR bank
// swizzle + XCD swizzle; 2-phase __syncthreads dbuf.
// K-concat: for k0 >= wrapK, A source switches Alo->Ahi; k-index rebased.
// mode 0: f32 C. mode 1: bf16 C. mode 2: fused Mamba prep epilogue.
// ---------------------------------------------------------------------------
__global__ __launch_bounds__(256) void gemm64(
    const unsigned short* __restrict__ Alo, const unsigned short* __restrict__ Ahi,
    const unsigned short* __restrict__ B, float* __restrict__ C,
    int M, int N, int K, int wrapK, int ks, int mode,
    const float* __restrict__ A_log, const unsigned short* __restrict__ u_in,
    unsigned* __restrict__ ddu_out,
    unsigned short* __restrict__ Bbf, unsigned short* __restrict__ Cbf)
{
    __shared__ short As0[64 * 64];
    __shared__ short Bs0[64 * 64];
    __shared__ short As1[64 * 64];
    __shared__ short Bs1[64 * 64];
    const int tid  = threadIdx.x;
    const int lane = tid & 63, wid = tid >> 6;

    // XCD-aware swizzle: contiguous work chunk per XCD (grid.x*grid.y % 8 == 0)
    const int gx = gridDim.x;
    int id  = blockIdx.y * gx + blockIdx.x;
    int q   = (gx * gridDim.y) >> 3;
    int swz = (id & 7) * q + (id >> 3);
    const int bm = (swz / gx) * 64, bn = (swz % gx) * 64;

    const int wm = (wid >> 1) * 32, wn = (wid & 1) * 32;
    const int fr = lane & 15;
    const int h  = fr & 7;                 // read-side bank swizzle
    const int tq = lane >> 4;
    const int Kc = K / ks;
    const int k0beg = blockIdx.z * Kc;
    const int nsteps = Kc / 64;
    float* Cz = C + (size_t)blockIdx.z * M * N;
    unsigned short* Czb = (unsigned short*)C + (size_t)blockIdx.z * M * N;

    // Hoisted A-source resolution (uniform per block: slices never cross wrapK)
    const unsigned short* Asrc;
    int ka0;
    if (k0beg >= wrapK) { Asrc = Ahi; ka0 = k0beg - wrapK; }
    else                { Asrc = Alo; ka0 = k0beg; }

    // Precompute the 4 per-thread global staging pointers (advance 128 B/step)
    const char* pA[2];
    const char* pB[2];
#pragma unroll
    for (int r = 0; r < 2; r++) {
        int o    = tid * 16 + r * 4096;
        int row  = o >> 7;
        int colb = ((((o >> 4) & 7) ^ (row & 7)) << 4);   // pre-swizzled source col
        pA[r] = (const char*)Asrc + ((size_t)(bm + row) * wrapK + ka0) * 2 + colb;
        pB[r] = (const char*)B    + ((size_t)(bn + row) * wrapK + ka0) * 2 + colb;
    }
    const int wbase = wid * 1024;

    f32x4 acc[2][2];
#pragma unroll
    for (int i = 0; i < 2; i++)
#pragma unroll
        for (int j = 0; j < 2; j++) acc[i][j] = (f32x4)0.f;

    auto STAGE = [&](short* Adst, short* Bdst) {
#pragma unroll
        for (int r = 0; r < 2; r++) { gload16(pA[r], (char*)Adst + wbase + r * 4096); pA[r] += 128; }
#pragma unroll
        for (int r = 0; r < 2; r++) { gload16(pB[r], (char*)Bdst + wbase + r * 4096); pB[r] += 128; }
    };
    auto COMPUTE = [&](const short* Asrc_l, const short* Bsrc_l) {
#pragma unroll
        for (int kk = 0; kk < 2; kk++) {
            const int sc = ((kk * 4 + tq) ^ h) << 3;     // swizzled chunk (shorts)
            bf16x8 af[2], bfr[2];
#pragma unroll
            for (int i = 0; i < 2; i++)
                af[i] = *reinterpret_cast<const bf16x8*>(&Asrc_l[(wm + i * 16 + fr) * 64 + sc]);
#pragma unroll
            for (int j = 0; j < 2; j++)
                bfr[j] = *reinterpret_cast<const bf16x8*>(&Bsrc_l[(wn + j * 16 + fr) * 64 + sc]);
#pragma unroll
            for (int i = 0; i < 2; i++)
#pragma unroll
                for (int j = 0; j < 2; j++)
                    acc[i][j] = __builtin_amdgcn_mfma_f32_16x16x32_bf16(af[i], bfr[j], acc[i][j], 0, 0, 0);
        }
    };

    // 2-phase pipeline, unrolled x2 with distinct buffers
    STAGE(As0, Bs0);
    __syncthreads();
    for (int st = 0; st < nsteps; st += 2) {
        if (st + 1 < nsteps) STAGE(As1, Bs1);
        COMPUTE(As0, Bs0);
        __syncthreads();
        if (st + 1 < nsteps) {
            if (st + 2 < nsteps) STAGE(As0, Bs0);
            COMPUTE(As1, Bs1);
            __syncthreads();
        }
    }

    const int crow = (lane >> 4) * 4;
    if (mode == 2) {
        if (bn < 1024) {                                 // delta region -> packed (dA|du)
#pragma unroll
            for (int j = 0; j < 2; j++) {
                int d = bn + wn + j * 16 + fr;
                float nAd = -fexp(A_log[d]);
#pragma unroll
                for (int i = 0; i < 2; i++)
#pragma unroll
                    for (int r = 0; r < 4; r++) {
                        int m = bm + wm + i * 16 + crow + r;
                        float delta = sp_f(acc[i][j][r]);
                        size_t idx = (size_t)m * DI + d;
                        float dA = fexp(delta * nAd);
                        float du = delta * bf2f(u_in[idx]);
                        ddu_out[idx] = (unsigned)f2bf(dA) | ((unsigned)f2bf(du) << 16);
                    }
            }
        } else {                                         // B/C pack region
#pragma unroll
            for (int j = 0; j < 2; j++) {
                int cc = bn + wn + j * 16 + fr;
#pragma unroll
                for (int i = 0; i < 2; i++)
#pragma unroll
                    for (int r = 0; r < 4; r++) {
                        int m = bm + wm + i * 16 + crow + r;
                        unsigned short v16 = f2bf(acc[i][j][r]);
                        if (cc < 1024 + NS) Bbf[(size_t)m * NS + cc - 1024]      = v16;
                        else                Cbf[(size_t)m * NS + cc - 1024 - NS] = v16;
                    }
            }
        }
    } else {
#pragma unroll
        for (int i = 0; i < 2; i++)
#pragma unroll
            for (int j = 0; j < 2; j++)
#pragma unroll
                for (int r = 0; r < 4; r++) {
                    size_t idx = (size_t)(bm + wm + i * 16 + crow + r) * N + (bn + wn + j * 16 + fr);
                    if (mode == 1) Czb[idx] = f2bf(acc[i][j][r]);
                    else           Cz[idx]  = acc[i][j][r];
                }
    }
}

// ---------------------------------------------------------------------------
// Split-K reduce (4 slices): out = p0+p1+p2+p3
// ---------------------------------------------------------------------------
__global__ __launch_bounds__(256) void reduce4(
    const float* __restrict__ p, float* __restrict__ out, int n)
{
    int i = (blockIdx.x * 256 + threadIdx.x) * 4;
    if (i >= n) return;
    float4 a = *(const float4*)(p + i);
    float4 b = *(const float4*)(p + n + i);
    float4 c = *(const float4*)(p + 2 * n + i);
    float4 d = *(const float4*)(p + 3 * n + i);
    float4 o;
    o.x = (a.x + b.x) + (c.x + d.x);
    o.y = (a.y + b.y) + (c.y + d.y);
    o.z = (a.z + b.z) + (c.z + d.z);
    o.w = (a.w + b.w) + (c.w + d.w);
    *(float4*)(out + i) = o;
}

// ---------------------------------------------------------------------------
// Conv (causal fwd + anti-causal bwd) + SiLU -> u; fused D*u and F=0.5*silu(z).
// Vectorized x4; fast-math silu.
// ---------------------------------------------------------------------------
__global__ __launch_bounds__(256) void convk(
    const unsigned short* __restrict__ xzb, const float* __restrict__ cw,
    const float* __restrict__ cb, const float* __restrict__ Dvec,
    unsigned short* __restrict__ uc2b, unsigned short* __restrict__ ygb,
    unsigned short* __restrict__ Fbuf)
{
    int idx = blockIdx.x * 256 + threadIdx.x;      // (b, tau, d4): 2*1024*256 total
    int b   = idx >> 18;
    int rem = idx & ((LSEQ * 256) - 1);
    int tau = rem >> 8;
    int d4  = (rem & 255) << 2;

    const unsigned short* xc = xzb + (size_t)b * LSEQ * (2 * DI);
    float xv[7][4];                                 // rows tau-3 .. tau+3
#pragma unroll
    for (int rr = 0; rr < 7; rr++) {
        int t = tau - 3 + rr;
        if (t >= 0 && t < LSEQ) {
            ushort4 v = *(const ushort4*)&xc[(size_t)t * 2048 + d4];
            xv[rr][0] = bf2f(v.x); xv[rr][1] = bf2f(v.y);
            xv[rr][2] = bf2f(v.z); xv[rr][3] = bf2f(v.w);
        } else {
            xv[rr][0] = 0.f; xv[rr][1] = 0.f; xv[rr][2] = 0.f; xv[rr][3] = 0.f;
        }
    }
    ushort4 zv = *(const ushort4*)&xc[(size_t)tau * 2048 + DI + d4];
    float4 cbv = *(const float4*)&cb[d4];
    float4 Dv  = *(const float4*)&Dvec[d4];
    float cbA[4] = {cbv.x, cbv.y, cbv.z, cbv.w};
    float DA[4]  = {Dv.x, Dv.y, Dv.z, Dv.w};
    float zA[4]  = {bf2f(zv.x), bf2f(zv.y), bf2f(zv.z), bf2f(zv.w)};

    unsigned short ufb[4], ubb[4], yfb[4], ybb[4], Ff[4];
#pragma unroll
    for (int j = 0; j < 4; j++) {
        float4 w = *(const float4*)&cw[(size_t)(d4 + j) * 4];
        float accf = fmaf(w.x, xv[0][j], fmaf(w.y, xv[1][j], fmaf(w.z, xv[2][j], fmaf(w.w, xv[3][j], cbA[j]))));
        float accb = fmaf(w.x, xv[6][j], fmaf(w.y, xv[5][j], fmaf(w.z, xv[4][j], fmaf(w.w, xv[3][j], cbA[j]))));
        float uf = silu_f(accf), ub = silu_f(accb);
        ufb[j] = f2bf(uf); ubb[j] = f2bf(ub);
        yfb[j] = f2bf(DA[j] * uf); ybb[j] = f2bf(DA[j] * ub);
        Ff[j]  = f2bf(0.5f * silu_f(zA[j]));
    }
    size_t fi = ((size_t)b * LSEQ + tau) * DI + d4;
    size_t bi = ((size_t)(2 + b) * LSEQ + tau) * DI + d4;
    *(ushort4*)&uc2b[fi] = *(ushort4*)ufb;
    *(ushort4*)&uc2b[bi] = *(ushort4*)ubb;
    *(ushort4*)&ygb[fi]  = *(ushort4*)yfb;
    *(ushort4*)&ygb[bi]  = *(ushort4*)ybb;
    *(ushort4*)&Fbuf[fi] = *(ushort4*)Ff;
}

// ---------------------------------------------------------------------------
// Pass A: local chunk scan from zero, TC=32 (24 KB LDS -> 6 blocks/CU).
// R20: 2-deep register prefetch of the ddu/ygb streams (2x memory-level
// parallelism per thread against the ~500-cyc strided L2 latency).
// ---------------------------------------------------------------------------
__global__ __launch_bounds__(256) void passA(
    const unsigned* __restrict__ ddu,
    const unsigned short* __restrict__ Bbf, const unsigned short* __restrict__ Cbf,
    unsigned short* __restrict__ ygb, unsigned short* __restrict__ gbuf,
    unsigned short* __restrict__ sEnd, float* __restrict__ Pbuf)
{
    const int dl   = threadIdx.x >> 2;
    const int nq   = threadIdx.x & 3;
    const int d0   = blockIdx.x * 64;
    const int d    = d0 + dl;
    const int c    = blockIdx.y;
    const int dirb = blockIdx.z;
    const int dir  = dirb >> 1;

    __shared__ float Bsh[TC][NS];
    __shared__ float Csh[TC][NS];
    __shared__ unsigned short gshY[TC][64];
    __shared__ unsigned short gshG[TC][64];

    for (int i = threadIdx.x * 4; i < TC * NS; i += 1024) {
        int tl = i >> 6, n = i & 63;
        int tau = dir ? (LSEQ - 1 - (c * TC + tl)) : (c * TC + tl);
        ushort4 vb = *(const ushort4*)&Bbf[((size_t)dirb * LSEQ + tau) * NS + n];
        ushort4 vc = *(const ushort4*)&Cbf[((size_t)dirb * LSEQ + tau) * NS + n];
        Bsh[tl][n+0] = bf2f(vb.x); Bsh[tl][n+1] = bf2f(vb.y);
        Bsh[tl][n+2] = bf2f(vb.z); Bsh[tl][n+3] = bf2f(vb.w);
        Csh[tl][n+0] = bf2f(vc.x); Csh[tl][n+1] = bf2f(vc.y);
        Csh[tl][n+2] = bf2f(vc.z); Csh[tl][n+3] = bf2f(vc.w);
    }
    __syncthreads();

    float s[16];
#pragma unroll
    for (int i = 0; i < 16; i++) s[i] = 0.f;
    float g_run = 1.f;

    int tau0 = dir ? (LSEQ - 1 - c * TC) : (c * TC);
    long stp = (dir ? -1L : 1L) * (long)DI;
    const unsigned* pW = ddu + ((size_t)dirb * LSEQ + tau0) * DI + d;
    const unsigned short* pY = ygb + ((size_t)dirb * LSEQ + tau0) * DI + d;

    unsigned wA = *pW;
    float DuA = bf2f(*pY);
    pW += stp; pY += stp;
    unsigned wB = *pW;
    float DuB = bf2f(*pY);
    for (int tl = 0; tl < TC; tl++) {
        unsigned w_c = wA;
        float Du_c = DuA;
        wA = wB; DuA = DuB;
        if (tl + 2 < TC) {                        // 2-deep register prefetch
            pW += stp; pY += stp;
            wB = *pW; DuB = bf2f(*pY);
        }
        float dA_c = bf2f((unsigned short)(w_c & 0xffff));
        float du_c = bf2f((unsigned short)(w_c >> 16));
        g_run *= dA_c;
        float ydot = 0.f;
        const float4* brow = (const float4*)&Bsh[tl][nq * 16];
        const float4* crow = (const float4*)&Csh[tl][nq * 16];
#pragma unroll
        for (int q = 0; q < 4; q++) {
            float4 bv = brow[q];
            float4 cv = crow[q];
            float s0 = fmaf(du_c, bv.x, dA_c * s[4*q+0]); s[4*q+0] = s0; ydot = fmaf(cv.x, s0, ydot);
            float s1 = fmaf(du_c, bv.y, dA_c * s[4*q+1]); s[4*q+1] = s1; ydot = fmaf(cv.y, s1, ydot);
            float s2 = fmaf(du_c, bv.z, dA_c * s[4*q+2]); s[4*q+2] = s2; ydot = fmaf(cv.z, s2, ydot);
            float s3 = fmaf(du_c, bv.w, dA_c * s[4*q+3]); s[4*q+3] = s3; ydot = fmaf(cv.w, s3, ydot);
        }
        ydot += __shfl_xor(ydot, 1);
        ydot += __shfl_xor(ydot, 2);
        if (nq == 0) {
            gshY[tl][dl] = f2bf(Du_c + ydot);
            gshG[tl][dl] = f2bf(g_run);
        }
    }
    __syncthreads();

    size_t base = (((size_t)dirb * NC + c) * DI + d) * NS + nq * 16;
#pragma unroll
    for (int q = 0; q < 4; q++) {
        ushort4 v;
        v.x = f2bf(s[4*q+0]); v.y = f2bf(s[4*q+1]);
        v.z = f2bf(s[4*q+2]); v.w = f2bf(s[4*q+3]);
        *(ushort4*)&sEnd[base + q * 4] = v;
    }
    if (nq == 0) Pbuf[((size_t)dirb * NC + c) * DI + d] = g_run;

    for (int i = threadIdx.x * 4; i < TC * 64; i += 1024) {
        int tl = i >> 6, col = i & 63;
        int tau = dir ? (LSEQ - 1 - (c * TC + tl)) : (c * TC + tl);
        *(ushort4*)&ygb[((size_t)dirb * LSEQ + tau) * DI + d0 + col]  = *(const ushort4*)&gshY[tl][col];
        *(ushort4*)&gbuf[((size_t)dirb * LSEQ + tau) * DI + d0 + col] = *(const ushort4*)&gshG[tl][col];
    }
}

// ---------------------------------------------------------------------------
// Pass B: combine chunk states (NC=32), vectorized x2 (u32 = 2 bf16 lanes).
// ---------------------------------------------------------------------------
__global__ __launch_bounds__(256) void passB(
    const unsigned* __restrict__ sEnd2, const float* __restrict__ Pbuf,
    unsigned* __restrict__ sInit2)
{
    const int fl   = blockIdx.x * 256 + threadIdx.x;   // d*32 + npair
    const int dirb = blockIdx.y;
    const int d    = fl >> 5;
    float r0 = 0.f, r1 = 0.f;
    for (int c = 0; c < NC; c++) {
        size_t idx = ((size_t)(dirb * NC + c)) * (DI * NS / 2) + fl;
        unsigned v = sEnd2[idx];
        float t0 = bf2f((unsigned short)(v & 0xffff));
        float t1 = bf2f((unsigned short)(v >> 16));
        sInit2[idx] = (unsigned)f2bf(r0) | ((unsigned)f2bf(r1) << 16);
        float P = Pbuf[((size_t)dirb * NC + c) * DI + d];
        r0 = fmaf(P, r0, t0);
        r1 = fmaf(P, r1, t1);
    }
}

// ---------------------------------------------------------------------------
// corrK: per (dirb, chunk=32, 128-d group): corr = C_chunk[32,64] @ s_init^T
// via MFMA (padded LDS), then out = F*(yloc + g*corr) -> ygb in place.
// ---------------------------------------------------------------------------
__global__ __launch_bounds__(256) void corrK(
    const unsigned short* __restrict__ Cbf, const unsigned short* __restrict__ sInitB,
    const unsigned short* __restrict__ gbuf, const unsigned short* __restrict__ Fbuf,
    unsigned short* __restrict__ ygb)
{
    const int tid  = threadIdx.x;
    const int lane = tid & 63, wid = tid >> 6;
    const int d0   = blockIdx.x * 128;
    const int c    = blockIdx.y;
    const int dirb = blockIdx.z;
    const int dir  = dirb >> 1;
    const int b    = dirb & 1;
    const int fr = lane & 15, fk = (lane >> 4) * 8;
    const int wn = wid * 32;

    __shared__ short Cs[TC * LDP];
    __shared__ short Ss[128 * LDP];
    __shared__ float corrS[TC * 128];

    for (int i = tid * 4; i < TC * 64; i += 1024) {
        int tl = i >> 6, n = i & 63;
        int tau = dir ? (LSEQ - 1 - (c * TC + tl)) : (c * TC + tl);
        *(ushort4*)&Cs[tl * LDP + n] = *(const ushort4*)&Cbf[((size_t)dirb * LSEQ + tau) * NS + n];
    }
    for (int i = tid * 4; i < 128 * 64; i += 1024) {
        int r = i >> 6, n = i & 63;
        *(ushort4*)&Ss[r * LDP + n] =
            *(const ushort4*)&sInitB[(((size_t)dirb * NC + c) * DI + d0 + r) * NS + n];
    }
    __syncthreads();

    f32x4 acc[2][2];
#pragma unroll
    for (int i = 0; i < 2; i++)
#pragma unroll
        for (int j = 0; j < 2; j++) acc[i][j] = (f32x4)0.f;

#pragma unroll
    for (int kk = 0; kk < 2; kk++) {
        bf16x8 af[2], bfr[2];
#pragma unroll
        for (int i = 0; i < 2; i++)
            af[i] = *reinterpret_cast<const bf16x8*>(&Cs[(i * 16 + fr) * LDP + kk * 32 + fk]);
#pragma unroll
        for (int j = 0; j < 2; j++)
            bfr[j] = *reinterpret_cast<const bf16x8*>(&Ss[(wn + j * 16 + fr) * LDP + kk * 32 + fk]);
#pragma unroll
        for (int i = 0; i < 2; i++)
#pragma unroll
            for (int j = 0; j < 2; j++)
                acc[i][j] = __builtin_amdgcn_mfma_f32_16x16x32_bf16(af[i], bfr[j], acc[i][j], 0, 0, 0);
    }

    const int crow = (lane >> 4) * 4;
#pragma unroll
    for (int i = 0; i < 2; i++)
#pragma unroll
        for (int j = 0; j < 2; j++)
#pragma unroll
            for (int r = 0; r < 4; r++)
                corrS[(i * 16 + crow + r) * 128 + (wn + j * 16 + fr)] = acc[i][j][r];
    __syncthreads();

    for (int i = tid * 4; i < TC * 128; i += 1024) {
        int tl = i >> 7, col = i & 127;
        int tau = dir ? (LSEQ - 1 - (c * TC + tl)) : (c * TC + tl);
        size_t gi = ((size_t)dirb * LSEQ + tau) * DI + d0 + col;
        size_t fi = ((size_t)b    * LSEQ + tau) * DI + d0 + col;
        ushort4 g4 = *(const ushort4*)&gbuf[gi];
        ushort4 y4 = *(const ushort4*)&ygb[gi];
        ushort4 F4 = *(const ushort4*)&Fbuf[fi];
        const float* cr = &corrS[tl * 128 + col];
        ushort4 o;
        o.x = f2bf(bf2f(F4.x) * fmaf(bf2f(g4.x), cr[0], bf2f(y4.x)));
        o.y = f2bf(bf2f(F4.y) * fmaf(bf2f(g4.y), cr[1], bf2f(y4.y)));
        o.z = f2bf(bf2f(F4.z) * fmaf(bf2f(g4.z), cr[2], bf2f(y4.z)));
        o.w = f2bf(bf2f(F4.w) * fmaf(bf2f(g4.w), cr[3], bf2f(y4.w)));
        *(ushort4*)&ygb[gi] = o;
    }
}

// ---------------------------------------------------------------------------
extern "C" void kernel_launch(void* const* d_in, const int* in_sizes, int n_in,
                              void* d_out, int out_size, void* d_ws, size_t ws_size,
                              hipStream_t stream)
{
    const float* x      = (const float*)d_in[0];
    const float* W_in   = (const float*)d_in[1];
    const float* conv_w = (const float*)d_in[2];
    const float* conv_b = (const float*)d_in[3];
    const float* W_xprj = (const float*)d_in[4];
    const float* A_log  = (const float*)d_in[5];
    const float* Dvec   = (const float*)d_in[6];
    const float* W_out  = (const float*)d_in[7];
    float* out = (float*)d_out;

    // workspace ~57.2 MB; aliases are dead-before-overwrite (stream order):
    float* ws = (float*)d_ws;
    unsigned*       ddu   = (unsigned*)ws;                        // [4096][1024] u32 (dA|du), 16.8 MB
    unsigned short* uc2b  = (unsigned short*)(ws + 4194304);      // u, 8.4 MB
    unsigned short* xzb   = uc2b + 4194304;                       // 8.4 MB
    unsigned short* ygb   = xzb  + 4194304;                       // Du->yloc->g, 8.4 MB
    unsigned short* gbuf  = ygb  + 4194304;                       // 8.4 MB
    unsigned short* Fbuf  = gbuf + 4194304;                       // 4.2 MB
    unsigned short* Bbf   = Fbuf + 2097152;                       // 0.5 MB
    unsigned short* Cbf   = Bbf  + 262144;                        // 0.5 MB
    unsigned short* wob   = Cbf  + 262144;                        // 1.0 MB
    float*          Pbuf  = (float*)(wob + 524288);               // [4][32][1024] f32, 0.5 MB
    // aliases:
    unsigned short* xb     = (unsigned short*)ddu;                // dead after gemm1 (ddu written by gemm2)
    unsigned short* winb   = xb + 1048576;                        // dead after gemm1
    unsigned short* wxb    = gbuf;                                // dead after gemm2 (gbuf written in passA)
    unsigned short* sEnd   = uc2b;                                // 16.8 MB over uc2b+xzb (dead after gemm2/convk)
    unsigned short* sInitB = (unsigned short*)ddu;                // 16.8 MB (ddu dead after passA)
    float*          gpart  = (float*)ddu;                         // gemm3 partials (sInitB dead after corrK)

    // 1) bf16 casts
    castall<<<3712, 256, 0, stream>>>(x, W_in, W_xprj, W_out, xb, winb, wxb, wob);

    // 2) xz = x @ W_in^T -> bf16 (M=2048, N=2048, K=512) — 1024 blocks
    gemm64<<<dim3(32, 32), 256, 0, stream>>>(xb, nullptr, winb, (float*)xzb,
        B_ * LSEQ, 2 * DI, DM, DM, 1, 1, nullptr, nullptr, nullptr, nullptr, nullptr);

    // 3) conv both dirs + SiLU -> u; fused D*u and F=0.5*silu(z) — vec x4
    convk<<<2048, 256, 0, stream>>>(xzb, conv_w, conv_b, Dvec, uc2b, ygb, Fbuf);

    // 4) proj GEMM with fused prep epilogue: packed ddu + B,C — 1152 blocks
    gemm64<<<dim3(18, 64), 256, 0, stream>>>(uc2b, nullptr, wxb, nullptr,
        4 * LSEQ, DI + 2 * NS, DI, DI, 1, 2, A_log, uc2b, ddu, Bbf, Cbf);

    // 5) pass A: local scans + yloc + g — 2048 blocks, 24 KB LDS
    passA<<<dim3(16, NC, 4), 256, 0, stream>>>(ddu, Bbf, Cbf, ygb, gbuf, sEnd, Pbuf);

    // 6) pass B: chunk-state combine -> bf16 s_init — vec x2
    passB<<<dim3(128, 4), 256, 0, stream>>>((const unsigned*)sEnd, Pbuf, (unsigned*)sInitB);

    // 7) corrK: MFMA correction + epilogue -> final g values in ygb — 1024 blocks
    corrK<<<dim3(8, NC, 4), 256, 0, stream>>>(Cbf, sInitB, gbuf, Fbuf, ygb);

    // 8) out = [gf | gb] @ [W|W]^T via K-concat (K=2048, wrapK=1024), split-K=4 — 1024 blocks
    gemm64<<<dim3(8, 32, 4), 256, 0, stream>>>(ygb, ygb + (size_t)2 * LSEQ * DI, wob, gpart,
        B_ * LSEQ, DM, 2 * DI, DI, 4, 0, nullptr, nullptr, nullptr, nullptr, nullptr);
    reduce4<<<1024, 256, 0, stream>>>(gpart, out, B_ * LSEQ * DM);
}

// Round 21
// 122.628 us; speedup vs baseline: 1.0657x; 1.0657x over previous
//
#include <hip/hip_runtime.h>
#include <math.h>

#define B_    2
#define LSEQ  1024
#define DM    512
#define DI    1024
#define NS    64
#define TC    32
#define NC    (LSEQ/TC)     // 32
#define LDP   72            // padded stride for corrK tiles only

typedef __bf16 bf16x8 __attribute__((ext_vector_type(8)));
typedef float  f32x4  __attribute__((ext_vector_type(4)));

// fast-math transcendentals: native v_exp_f32 / v_log_f32 / v_rcp_f32.
__device__ __forceinline__ float fexp(float x)   { return __expf(x); }
__device__ __forceinline__ float sp_f(float x)   { return fmaxf(x, 0.f) + __logf(1.f + __expf(-fabsf(x))); }
__device__ __forceinline__ float silu_f(float x) { return x * __builtin_amdgcn_rcpf(1.f + __expf(-x)); }
__device__ __forceinline__ unsigned short f2bf(float f) {
    unsigned int u = __float_as_uint(f);
    u += 0x7FFF + ((u >> 16) & 1);          // RNE
    return (unsigned short)(u >> 16);
}
__device__ __forceinline__ float bf2f(unsigned short h) {
    return __uint_as_float(((unsigned int)h) << 16);
}
// async global->LDS, 16 B per lane; LDS dest = wave-uniform base + lane*16
__device__ __forceinline__ void gload16(const void* g, void* l) {
    __builtin_amdgcn_global_load_lds(
        (const __attribute__((address_space(1))) unsigned int*)g,
        (__attribute__((address_space(3))) unsigned int*)l, 16, 0, 0);
}

// ---------------------------------------------------------------------------
// All 4 f32->bf16 casts in one launch (3712 blocks exactly).
// ---------------------------------------------------------------------------
__global__ __launch_bounds__(256) void castall(
    const float* __restrict__ x, const float* __restrict__ W_in,
    const float* __restrict__ W_xproj, const float* __restrict__ W_out,
    unsigned short* __restrict__ xb, unsigned short* __restrict__ winb,
    unsigned short* __restrict__ wxb, unsigned short* __restrict__ wob)
{
    int i = (blockIdx.x * 256 + threadIdx.x) * 4;
    const float* s; unsigned short* dst; int off;
    if (i < 1048576)      { s = x;       dst = xb;   off = i; }
    else if (i < 2097152) { s = W_in;    dst = winb; off = i - 1048576; }
    else if (i < 3276800) { s = W_xproj; dst = wxb;  off = i - 2097152; }
    else                  { s = W_out;   dst = wob;  off = i - 3276800; }
    float4 v = *(const float4*)(s + off);
    ushort4 o;
    o.x = f2bf(v.x); o.y = f2bf(v.y); o.z = f2bf(v.z); o.w = f2bf(v.w);
    *(ushort4*)(dst + off) = o;
}

// ---------------------------------------------------------------------------
// bf16 MFMA GEMM: 64x64 tile, BK=64, 4 waves in 2x2 (each 32x32, acc[2][2]).
// R17 structure (proven best, 122.7 us): gload_lds + both-sides XOR bank
// swizzle + XCD swizzle; 2-phase __syncthreads dbuf.
// K-concat: for k0 >= wrapK, A source switches Alo->Ahi; k-index rebased.
// mode 0: f32 C. mode 1: bf16 C. mode 2: fused Mamba prep epilogue.
// ---------------------------------------------------------------------------
__global__ __launch_bounds__(256) void gemm64(
    const unsigned short* __restrict__ Alo, const unsigned short* __restrict__ Ahi,
    const unsigned short* __restrict__ B, float* __restrict__ C,
    int M, int N, int K, int wrapK, int ks, int mode,
    const float* __restrict__ A_log, const unsigned short* __restrict__ u_in,
    unsigned* __restrict__ ddu_out,
    unsigned short* __restrict__ Bbf, unsigned short* __restrict__ Cbf)
{
    __shared__ short As0[64 * 64];
    __shared__ short Bs0[64 * 64];
    __shared__ short As1[64 * 64];
    __shared__ short Bs1[64 * 64];
    const int tid  = threadIdx.x;
    const int lane = tid & 63, wid = tid >> 6;

    // XCD-aware swizzle: contiguous work chunk per XCD (grid.x*grid.y % 8 == 0)
    const int gx = gridDim.x;
    int id  = blockIdx.y * gx + blockIdx.x;
    int q   = (gx * gridDim.y) >> 3;
    int swz = (id & 7) * q + (id >> 3);
    const int bm = (swz / gx) * 64, bn = (swz % gx) * 64;

    const int wm = (wid >> 1) * 32, wn = (wid & 1) * 32;
    const int fr = lane & 15;
    const int h  = fr & 7;                 // read-side bank swizzle
    const int tq = lane >> 4;
    const int Kc = K / ks;
    const int k0beg = blockIdx.z * Kc;
    const int nsteps = Kc / 64;
    float* Cz = C + (size_t)blockIdx.z * M * N;
    unsigned short* Czb = (unsigned short*)C + (size_t)blockIdx.z * M * N;

    // Hoisted A-source resolution (uniform per block: slices never cross wrapK)
    const unsigned short* Asrc;
    int ka0;
    if (k0beg >= wrapK) { Asrc = Ahi; ka0 = k0beg - wrapK; }
    else                { Asrc = Alo; ka0 = k0beg; }

    // Precompute the 4 per-thread global staging pointers (advance 128 B/step)
    const char* pA[2];
    const char* pB[2];
#pragma unroll
    for (int r = 0; r < 2; r++) {
        int o    = tid * 16 + r * 4096;
        int row  = o >> 7;
        int colb = ((((o >> 4) & 7) ^ (row & 7)) << 4);   // pre-swizzled source col
        pA[r] = (const char*)Asrc + ((size_t)(bm + row) * wrapK + ka0) * 2 + colb;
        pB[r] = (const char*)B    + ((size_t)(bn + row) * wrapK + ka0) * 2 + colb;
    }
    const int wbase = wid * 1024;

    f32x4 acc[2][2];
#pragma unroll
    for (int i = 0; i < 2; i++)
#pragma unroll
        for (int j = 0; j < 2; j++) acc[i][j] = (f32x4)0.f;

    auto STAGE = [&](short* Adst, short* Bdst) {
#pragma unroll
        for (int r = 0; r < 2; r++) { gload16(pA[r], (char*)Adst + wbase + r * 4096); pA[r] += 128; }
#pragma unroll
        for (int r = 0; r < 2; r++) { gload16(pB[r], (char*)Bdst + wbase + r * 4096); pB[r] += 128; }
    };
    auto COMPUTE = [&](const short* Asrc_l, const short* Bsrc_l) {
#pragma unroll
        for (int kk = 0; kk < 2; kk++) {
            const int sc = ((kk * 4 + tq) ^ h) << 3;     // swizzled chunk (shorts)
            bf16x8 af[2], bfr[2];
#pragma unroll
            for (int i = 0; i < 2; i++)
                af[i] = *reinterpret_cast<const bf16x8*>(&Asrc_l[(wm + i * 16 + fr) * 64 + sc]);
#pragma unroll
            for (int j = 0; j < 2; j++)
                bfr[j] = *reinterpret_cast<const bf16x8*>(&Bsrc_l[(wn + j * 16 + fr) * 64 + sc]);
#pragma unroll
            for (int i = 0; i < 2; i++)
#pragma unroll
                for (int j = 0; j < 2; j++)
                    acc[i][j] = __builtin_amdgcn_mfma_f32_16x16x32_bf16(af[i], bfr[j], acc[i][j], 0, 0, 0);
        }
    };

    // 2-phase pipeline, unrolled x2 with distinct buffers
    STAGE(As0, Bs0);
    __syncthreads();
    for (int st = 0; st < nsteps; st += 2) {
        if (st + 1 < nsteps) STAGE(As1, Bs1);
        COMPUTE(As0, Bs0);
        __syncthreads();
        if (st + 1 < nsteps) {
            if (st + 2 < nsteps) STAGE(As0, Bs0);
            COMPUTE(As1, Bs1);
            __syncthreads();
        }
    }

    const int crow = (lane >> 4) * 4;
    if (mode == 2) {
        if (bn < 1024) {                                 // delta region -> packed (dA|du)
#pragma unroll
            for (int j = 0; j < 2; j++) {
                int d = bn + wn + j * 16 + fr;
                float nAd = -fexp(A_log[d]);
#pragma unroll
                for (int i = 0; i < 2; i++)
#pragma unroll
                    for (int r = 0; r < 4; r++) {
                        int m = bm + wm + i * 16 + crow + r;
                        float delta = sp_f(acc[i][j][r]);
                        size_t idx = (size_t)m * DI + d;
                        float dA = fexp(delta * nAd);
                        float du = delta * bf2f(u_in[idx]);
                        ddu_out[idx] = (unsigned)f2bf(dA) | ((unsigned)f2bf(du) << 16);
                    }
            }
        } else {                                         // B/C pack region
#pragma unroll
            for (int j = 0; j < 2; j++) {
                int cc = bn + wn + j * 16 + fr;
#pragma unroll
                for (int i = 0; i < 2; i++)
#pragma unroll
                    for (int r = 0; r < 4; r++) {
                        int m = bm + wm + i * 16 + crow + r;
                        unsigned short v16 = f2bf(acc[i][j][r]);
                        if (cc < 1024 + NS) Bbf[(size_t)m * NS + cc - 1024]      = v16;
                        else                Cbf[(size_t)m * NS + cc - 1024 - NS] = v16;
                    }
            }
        }
    } else {
#pragma unroll
        for (int i = 0; i < 2; i++)
#pragma unroll
            for (int j = 0; j < 2; j++)
#pragma unroll
                for (int r = 0; r < 4; r++) {
                    size_t idx = (size_t)(bm + wm + i * 16 + crow + r) * N + (bn + wn + j * 16 + fr);
                    if (mode == 1) Czb[idx] = f2bf(acc[i][j][r]);
                    else           Cz[idx]  = acc[i][j][r];
                }
    }
}

// ---------------------------------------------------------------------------
// Split-K reduce (4 slices): out = p0+p1+p2+p3
// ---------------------------------------------------------------------------
__global__ __launch_bounds__(256) void reduce4(
    const float* __restrict__ p, float* __restrict__ out, int n)
{
    int i = (blockIdx.x * 256 + threadIdx.x) * 4;
    if (i >= n) return;
    float4 a = *(const float4*)(p + i);
    float4 b = *(const float4*)(p + n + i);
    float4 c = *(const float4*)(p + 2 * n + i);
    float4 d = *(const float4*)(p + 3 * n + i);
    float4 o;
    o.x = (a.x + b.x) + (c.x + d.x);
    o.y = (a.y + b.y) + (c.y + d.y);
    o.z = (a.z + b.z) + (c.z + d.z);
    o.w = (a.w + b.w) + (c.w + d.w);
    *(float4*)(out + i) = o;
}

// ---------------------------------------------------------------------------
// Conv (causal fwd + anti-causal bwd) + SiLU -> u; fused D*u (-> Dub) and
// F=0.5*silu(z). Vectorized x4; fast-math silu.
// ---------------------------------------------------------------------------
__global__ __launch_bounds__(256) void convk(
    const unsigned short* __restrict__ xzb, const float* __restrict__ cw,
    const float* __restrict__ cb, const float* __restrict__ Dvec,
    unsigned short* __restrict__ uc2b, unsigned short* __restrict__ Dub,
    unsigned short* __restrict__ Fbuf)
{
    int idx = blockIdx.x * 256 + threadIdx.x;      // (b, tau, d4): 2*1024*256 total
    int b   = idx >> 18;
    int rem = idx & ((LSEQ * 256) - 1);
    int tau = rem >> 8;
    int d4  = (rem & 255) << 2;

    const unsigned short* xc = xzb + (size_t)b * LSEQ * (2 * DI);
    float xv[7][4];                                 // rows tau-3 .. tau+3
#pragma unroll
    for (int rr = 0; rr < 7; rr++) {
        int t = tau - 3 + rr;
        if (t >= 0 && t < LSEQ) {
            ushort4 v = *(const ushort4*)&xc[(size_t)t * 2048 + d4];
            xv[rr][0] = bf2f(v.x); xv[rr][1] = bf2f(v.y);
            xv[rr][2] = bf2f(v.z); xv[rr][3] = bf2f(v.w);
        } else {
            xv[rr][0] = 0.f; xv[rr][1] = 0.f; xv[rr][2] = 0.f; xv[rr][3] = 0.f;
        }
    }
    ushort4 zv = *(const ushort4*)&xc[(size_t)tau * 2048 + DI + d4];
    float4 cbv = *(const float4*)&cb[d4];
    float4 Dv  = *(const float4*)&Dvec[d4];
    float cbA[4] = {cbv.x, cbv.y, cbv.z, cbv.w};
    float DA[4]  = {Dv.x, Dv.y, Dv.z, Dv.w};
    float zA[4]  = {bf2f(zv.x), bf2f(zv.y), bf2f(zv.z), bf2f(zv.w)};

    unsigned short ufb[4], ubb[4], yfb[4], ybb[4], Ff[4];
#pragma unroll
    for (int j = 0; j < 4; j++) {
        float4 w = *(const float4*)&cw[(size_t)(d4 + j) * 4];
        float accf = fmaf(w.x, xv[0][j], fmaf(w.y, xv[1][j], fmaf(w.z, xv[2][j], fmaf(w.w, xv[3][j], cbA[j]))));
        float accb = fmaf(w.x, xv[6][j], fmaf(w.y, xv[5][j], fmaf(w.z, xv[4][j], fmaf(w.w, xv[3][j], cbA[j]))));
        float uf = silu_f(accf), ub = silu_f(accb);
        ufb[j] = f2bf(uf); ubb[j] = f2bf(ub);
        yfb[j] = f2bf(DA[j] * uf); ybb[j] = f2bf(DA[j] * ub);
        Ff[j]  = f2bf(0.5f * silu_f(zA[j]));
    }
    size_t fi = ((size_t)b * LSEQ + tau) * DI + d4;
    size_t bi = ((size_t)(2 + b) * LSEQ + tau) * DI + d4;
    *(ushort4*)&uc2b[fi] = *(ushort4*)ufb;
    *(ushort4*)&uc2b[bi] = *(ushort4*)ubb;
    *(ushort4*)&Dub[fi]  = *(ushort4*)yfb;
    *(ushort4*)&Dub[bi]  = *(ushort4*)ybb;
    *(ushort4*)&Fbuf[fi] = *(ushort4*)Ff;
}

// ---------------------------------------------------------------------------
// Pass A: local chunk scan from zero, TC=32 (24 KB LDS -> 6 blocks/CU).
// R21: the Du stream is REMOVED from the inner loop (moved to corrK's
// coalesced epilogue) — one strided load stream (ddu) remains. 1-deep
// register prefetch (R20's 2-deep regressed).
// Emits yloc = C.s_loc (into ygb), g, chunk states, P.
// ---------------------------------------------------------------------------
__global__ __launch_bounds__(256) void passA(
    const unsigned* __restrict__ ddu,
    const unsigned short* __restrict__ Bbf, const unsigned short* __restrict__ Cbf,
    unsigned short* __restrict__ ygb, unsigned short* __restrict__ gbuf,
    unsigned short* __restrict__ sEnd, float* __restrict__ Pbuf)
{
    const int dl   = threadIdx.x >> 2;
    const int nq   = threadIdx.x & 3;
    const int d0   = blockIdx.x * 64;
    const int d    = d0 + dl;
    const int c    = blockIdx.y;
    const int dirb = blockIdx.z;
    const int dir  = dirb >> 1;

    __shared__ float Bsh[TC][NS];
    __shared__ float Csh[TC][NS];
    __shared__ unsigned short gshY[TC][64];
    __shared__ unsigned short gshG[TC][64];

    for (int i = threadIdx.x * 4; i < TC * NS; i += 1024) {
        int tl = i >> 6, n = i & 63;
        int tau = dir ? (LSEQ - 1 - (c * TC + tl)) : (c * TC + tl);
        ushort4 vb = *(const ushort4*)&Bbf[((size_t)dirb * LSEQ + tau) * NS + n];
        ushort4 vc = *(const ushort4*)&Cbf[((size_t)dirb * LSEQ + tau) * NS + n];
        Bsh[tl][n+0] = bf2f(vb.x); Bsh[tl][n+1] = bf2f(vb.y);
        Bsh[tl][n+2] = bf2f(vb.z); Bsh[tl][n+3] = bf2f(vb.w);
        Csh[tl][n+0] = bf2f(vc.x); Csh[tl][n+1] = bf2f(vc.y);
        Csh[tl][n+2] = bf2f(vc.z); Csh[tl][n+3] = bf2f(vc.w);
    }
    __syncthreads();

    float s[16];
#pragma unroll
    for (int i = 0; i < 16; i++) s[i] = 0.f;
    float g_run = 1.f;

    int tau0 = dir ? (LSEQ - 1 - c * TC) : (c * TC);
    long stp = (dir ? -1L : 1L) * (long)DI;
    const unsigned* pW = ddu + ((size_t)dirb * LSEQ + tau0) * DI + d;

    unsigned w = *pW;
    for (int tl = 0; tl < TC; tl++) {
        unsigned w_c = w;
        if (tl + 1 < TC) {                        // 1-deep register prefetch
            pW += stp;
            w = *pW;
        }
        float dA_c = bf2f((unsigned short)(w_c & 0xffff));
        float du_c = bf2f((unsigned short)(w_c >> 16));
        g_run *= dA_c;
        float ydot = 0.f;
        const float4* brow = (const float4*)&Bsh[tl][nq * 16];
        const float4* crow = (const float4*)&Csh[tl][nq * 16];
#pragma unroll
        for (int q = 0; q < 4; q++) {
            float4 bv = brow[q];
            float4 cv = crow[q];
            float s0 = fmaf(du_c, bv.x, dA_c * s[4*q+0]); s[4*q+0] = s0; ydot = fmaf(cv.x, s0, ydot);
            float s1 = fmaf(du_c, bv.y, dA_c * s[4*q+1]); s[4*q+1] = s1; ydot = fmaf(cv.y, s1, ydot);
            float s2 = fmaf(du_c, bv.z, dA_c * s[4*q+2]); s[4*q+2] = s2; ydot = fmaf(cv.z, s2, ydot);
            float s3 = fmaf(du_c, bv.w, dA_c * s[4*q+3]); s[4*q+3] = s3; ydot = fmaf(cv.w, s3, ydot);
        }
        ydot += __shfl_xor(ydot, 1);
        ydot += __shfl_xor(ydot, 2);
        if (nq == 0) {
            gshY[tl][dl] = f2bf(ydot);
            gshG[tl][dl] = f2bf(g_run);
        }
    }
    __syncthreads();

    size_t base = (((size_t)dirb * NC + c) * DI + d) * NS + nq * 16;
#pragma unroll
    for (int q = 0; q < 4; q++) {
        ushort4 v;
        v.x = f2bf(s[4*q+0]); v.y = f2bf(s[4*q+1]);
        v.z = f2bf(s[4*q+2]); v.w = f2bf(s[4*q+3]);
        *(ushort4*)&sEnd[base + q * 4] = v;
    }
    if (nq == 0) Pbuf[((size_t)dirb * NC + c) * DI + d] = g_run;

    for (int i = threadIdx.x * 4; i < TC * 64; i += 1024) {
        int tl = i >> 6, col = i & 63;
        int tau = dir ? (LSEQ - 1 - (c * TC + tl)) : (c * TC + tl);
        *(ushort4*)&ygb[((size_t)dirb * LSEQ + tau) * DI + d0 + col]  = *(const ushort4*)&gshY[tl][col];
        *(ushort4*)&gbuf[((size_t)dirb * LSEQ + tau) * DI + d0 + col] = *(const ushort4*)&gshG[tl][col];
    }
}

// ---------------------------------------------------------------------------
// Pass B: combine chunk states (NC=32), vectorized x2 (u32 = 2 bf16 lanes).
// ---------------------------------------------------------------------------
__global__ __launch_bounds__(256) void passB(
    const unsigned* __restrict__ sEnd2, const float* __restrict__ Pbuf,
    unsigned* __restrict__ sInit2)
{
    const int fl   = blockIdx.x * 256 + threadIdx.x;   // d*32 + npair
    const int dirb = blockIdx.y;
    const int d    = fl >> 5;
    float r0 = 0.f, r1 = 0.f;
    for (int c = 0; c < NC; c++) {
        size_t idx = ((size_t)(dirb * NC + c)) * (DI * NS / 2) + fl;
        unsigned v = sEnd2[idx];
        float t0 = bf2f((unsigned short)(v & 0xffff));
        float t1 = bf2f((unsigned short)(v >> 16));
        sInit2[idx] = (unsigned)f2bf(r0) | ((unsigned)f2bf(r1) << 16);
        float P = Pbuf[((size_t)dirb * NC + c) * DI + d];
        r0 = fmaf(P, r0, t0);
        r1 = fmaf(P, r1, t1);
    }
}

// ---------------------------------------------------------------------------
// corrK: per (dirb, chunk=32, 128-d group): corr = C_chunk[32,64] @ s_init^T
// via MFMA (padded LDS), then out = F*(Du + yloc + g*corr) -> ygb in place.
// (Du folded here from the coalesced Dub buffer — removed from passA.)
// ---------------------------------------------------------------------------
__global__ __launch_bounds__(256) void corrK(
    const unsigned short* __restrict__ Cbf, const unsigned short* __restrict__ sInitB,
    const unsigned short* __restrict__ gbuf, const unsigned short* __restrict__ Fbuf,
    const unsigned short* __restrict__ Dub, unsigned short* __restrict__ ygb)
{
    const int tid  = threadIdx.x;
    const int lane = tid & 63, wid = tid >> 6;
    const int d0   = blockIdx.x * 128;
    const int c    = blockIdx.y;
    const int dirb = blockIdx.z;
    const int dir  = dirb >> 1;
    const int b    = dirb & 1;
    const int fr = lane & 15, fk = (lane >> 4) * 8;
    const int wn = wid * 32;

    __shared__ short Cs[TC * LDP];
    __shared__ short Ss[128 * LDP];
    __shared__ float corrS[TC * 128];

    for (int i = tid * 4; i < TC * 64; i += 1024) {
        int tl = i >> 6, n = i & 63;
        int tau = dir ? (LSEQ - 1 - (c * TC + tl)) : (c * TC + tl);
        *(ushort4*)&Cs[tl * LDP + n] = *(const ushort4*)&Cbf[((size_t)dirb * LSEQ + tau) * NS + n];
    }
    for (int i = tid * 4; i < 128 * 64; i += 1024) {
        int r = i >> 6, n = i & 63;
        *(ushort4*)&Ss[r * LDP + n] =
            *(const ushort4*)&sInitB[(((size_t)dirb * NC + c) * DI + d0 + r) * NS + n];
    }
    __syncthreads();

    f32x4 acc[2][2];
#pragma unroll
    for (int i = 0; i < 2; i++)
#pragma unroll
        for (int j = 0; j < 2; j++) acc[i][j] = (f32x4)0.f;

#pragma unroll
    for (int kk = 0; kk < 2; kk++) {
        bf16x8 af[2], bfr[2];
#pragma unroll
        for (int i = 0; i < 2; i++)
            af[i] = *reinterpret_cast<const bf16x8*>(&Cs[(i * 16 + fr) * LDP + kk * 32 + fk]);
#pragma unroll
        for (int j = 0; j < 2; j++)
            bfr[j] = *reinterpret_cast<const bf16x8*>(&Ss[(wn + j * 16 + fr) * LDP + kk * 32 + fk]);
#pragma unroll
        for (int i = 0; i < 2; i++)
#pragma unroll
            for (int j = 0; j < 2; j++)
                acc[i][j] = __builtin_amdgcn_mfma_f32_16x16x32_bf16(af[i], bfr[j], acc[i][j], 0, 0, 0);
    }

    const int crow = (lane >> 4) * 4;
#pragma unroll
    for (int i = 0; i < 2; i++)
#pragma unroll
        for (int j = 0; j < 2; j++)
#pragma unroll
            for (int r = 0; r < 4; r++)
                corrS[(i * 16 + crow + r) * 128 + (wn + j * 16 + fr)] = acc[i][j][r];
    __syncthreads();

    for (int i = tid * 4; i < TC * 128; i += 1024) {
        int tl = i >> 7, col = i & 127;
        int tau = dir ? (LSEQ - 1 - (c * TC + tl)) : (c * TC + tl);
        size_t gi = ((size_t)dirb * LSEQ + tau) * DI + d0 + col;
        size_t fi = ((size_t)b    * LSEQ + tau) * DI + d0 + col;
        ushort4 g4 = *(const ushort4*)&gbuf[gi];
        ushort4 y4 = *(const ushort4*)&ygb[gi];
        ushort4 D4 = *(const ushort4*)&Dub[gi];
        ushort4 F4 = *(const ushort4*)&Fbuf[fi];
        const float* cr = &corrS[tl * 128 + col];
        ushort4 o;
        o.x = f2bf(bf2f(F4.x) * (bf2f(D4.x) + fmaf(bf2f(g4.x), cr[0], bf2f(y4.x))));
        o.y = f2bf(bf2f(F4.y) * (bf2f(D4.y) + fmaf(bf2f(g4.y), cr[1], bf2f(y4.y))));
        o.z = f2bf(bf2f(F4.z) * (bf2f(D4.z) + fmaf(bf2f(g4.z), cr[2], bf2f(y4.z))));
        o.w = f2bf(bf2f(F4.w) * (bf2f(D4.w) + fmaf(bf2f(g4.w), cr[3], bf2f(y4.w))));
        *(ushort4*)&ygb[gi] = o;
    }
}

// ---------------------------------------------------------------------------
extern "C" void kernel_launch(void* const* d_in, const int* in_sizes, int n_in,
                              void* d_out, int out_size, void* d_ws, size_t ws_size,
                              hipStream_t stream)
{
    const float* x      = (const float*)d_in[0];
    const float* W_in   = (const float*)d_in[1];
    const float* conv_w = (const float*)d_in[2];
    const float* conv_b = (const float*)d_in[3];
    const float* W_xprj = (const float*)d_in[4];
    const float* A_log  = (const float*)d_in[5];
    const float* Dvec   = (const float*)d_in[6];
    const float* W_out  = (const float*)d_in[7];
    float* out = (float*)d_out;

    // workspace ~65.6 MB; aliases are dead-before-overwrite (stream order):
    float* ws = (float*)d_ws;
    unsigned*       ddu   = (unsigned*)ws;                        // [4096][1024] u32 (dA|du), 16.8 MB
    unsigned short* uc2b  = (unsigned short*)(ws + 4194304);      // u, 8.4 MB
    unsigned short* xzb   = uc2b + 4194304;                       // 8.4 MB
    unsigned short* ygb   = xzb  + 4194304;                       // yloc->out, 8.4 MB
    unsigned short* gbuf  = ygb  + 4194304;                       // 8.4 MB
    unsigned short* Fbuf  = gbuf + 4194304;                       // 4.2 MB
    unsigned short* Bbf   = Fbuf + 2097152;                       // 0.5 MB
    unsigned short* Cbf   = Bbf  + 262144;                        // 0.5 MB
    unsigned short* wob   = Cbf  + 262144;                        // 1.0 MB
    float*          Pbuf  = (float*)(wob + 524288);               // [4][32][1024] f32, 0.5 MB
    unsigned short* Dub   = (unsigned short*)(Pbuf + 131072);     // D*u, 8.4 MB
    // aliases:
    unsigned short* xb     = (unsigned short*)ddu;                // dead after gemm1 (ddu written by gemm2)
    unsigned short* winb   = xb + 1048576;                        // dead after gemm1
    unsigned short* wxb    = gbuf;                                // dead after gemm2 (gbuf written in passA)
    unsigned short* sEnd   = uc2b;                                // 16.8 MB over uc2b+xzb (dead after gemm2/convk)
    unsigned short* sInitB = (unsigned short*)ddu;                // 16.8 MB (ddu dead after passA)
    float*          gpart  = (float*)ddu;                         // gemm3 partials (sInitB dead after corrK)

    // 1) bf16 casts
    castall<<<3712, 256, 0, stream>>>(x, W_in, W_xprj, W_out, xb, winb, wxb, wob);

    // 2) xz = x @ W_in^T -> bf16 (M=2048, N=2048, K=512) — 1024 blocks
    gemm64<<<dim3(32, 32), 256, 0, stream>>>(xb, nullptr, winb, (float*)xzb,
        B_ * LSEQ, 2 * DI, DM, DM, 1, 1, nullptr, nullptr, nullptr, nullptr, nullptr);

    // 3) conv both dirs + SiLU -> u; fused D*u (-> Dub) and F — vec x4
    convk<<<2048, 256, 0, stream>>>(xzb, conv_w, conv_b, Dvec, uc2b, Dub, Fbuf);

    // 4) proj GEMM with fused prep epilogue: packed ddu + B,C — 1152 blocks
    gemm64<<<dim3(18, 64), 256, 0, stream>>>(uc2b, nullptr, wxb, nullptr,
        4 * LSEQ, DI + 2 * NS, DI, DI, 1, 2, A_log, uc2b, ddu, Bbf, Cbf);

    // 5) pass A: local scans (single strided stream) + yloc + g — 2048 blocks
    passA<<<dim3(16, NC, 4), 256, 0, stream>>>(ddu, Bbf, Cbf, ygb, gbuf, sEnd, Pbuf);

    // 6) pass B: chunk-state combine -> bf16 s_init — vec x2
    passB<<<dim3(128, 4), 256, 0, stream>>>((const unsigned*)sEnd, Pbuf, (unsigned*)sInitB);

    // 7) corrK: MFMA correction + epilogue (adds Du) -> final g values in ygb
    corrK<<<dim3(8, NC, 4), 256, 0, stream>>>(Cbf, sInitB, gbuf, Fbuf, Dub, ygb);

    // 8) out = [gf | gb] @ [W|W]^T via K-concat (K=2048, wrapK=1024), split-K=4 — 1024 blocks
    gemm64<<<dim3(8, 32, 4), 256, 0, stream>>>(ygb, ygb + (size_t)2 * LSEQ * DI, wob, gpart,
        B_ * LSEQ, DM, 2 * DI, DI, 4, 0, nullptr, nullptr, nullptr, nullptr, nullptr);
    reduce4<<<1024, 256, 0, stream>>>(gpart, out, B_ * LSEQ * DM);
}